// Round 4
// baseline (154.827 us; speedup 1.0000x reference)
//
#include <hip/hip_runtime.h>

typedef float  f32x4  __attribute__((ext_vector_type(4)));
typedef short  bf16x8 __attribute__((ext_vector_type(8)));
typedef short  s16x4  __attribute__((ext_vector_type(4)));
typedef unsigned int u32x4 __attribute__((ext_vector_type(4)));

#define MFMA_BF16 __builtin_amdgcn_mfma_f32_16x16x32_bf16

__device__ __forceinline__ short f2bf(float f) {
  __bf16 h = (__bf16)f;
  return __builtin_bit_cast(short, h);
}

constexpr int S = 2048, D = 1024, H = 16, HD = 64;
constexpr int NT = S / 64;                 // 32 kv tiles
constexpr float SCALE = 0.125f;            // 1/sqrt(64)
constexpr float L2E = 1.44269504f;
constexpr float SL = SCALE * L2E;          // logits -> log2 domain in one mul

#define GLDS16(g, l) __builtin_amdgcn_global_load_lds( \
    (const __attribute__((address_space(1))) unsigned*)(g), \
    (__attribute__((address_space(3))) unsigned*)(l), 16, 0, 0)

#define WAITV(n) asm volatile("s_waitcnt vmcnt(" #n ")" ::: "memory")
#define SBAR()   __builtin_amdgcn_s_barrier()

// ---------------------------------------------------------------------------
// K/V prep: f32 [B,S,D] head-slices -> bf16 fragment-major tiles.
// ---------------------------------------------------------------------------
__global__ __launch_bounds__(256)
void kv_prep(const float* __restrict__ Kg, const float* __restrict__ Vg,
             short* __restrict__ Kb, short* __restrict__ Vb) {
  const int tile = blockIdx.x, h = blockIdx.y, b = blockIdx.z;
  const int t = threadIdx.x, lane = t & 63, w = t >> 6;
  const int lg = lane >> 4, lm = lane & 15;
  __shared__ short kt[64 * 68], vt[64 * 68];
  const float* kp = Kg + ((size_t)(b * S + tile * 64)) * D + h * HD;
  const float* vp = Vg + ((size_t)(b * S + tile * 64)) * D + h * HD;
  #pragma unroll
  for (int i = 0; i < 4; ++i) {
    int idx = i * 256 + t, r = idx >> 4, c4 = (idx & 15) * 4;
    float4 k4 = *(const float4*)(kp + (size_t)r * D + c4);
    s16x4 ks; ks[0]=f2bf(k4.x); ks[1]=f2bf(k4.y); ks[2]=f2bf(k4.z); ks[3]=f2bf(k4.w);
    *(s16x4*)&kt[r * 68 + c4] = ks;
    float4 v4 = *(const float4*)(vp + (size_t)r * D + c4);
    s16x4 vs; vs[0]=f2bf(v4.x); vs[1]=f2bf(v4.y); vs[2]=f2bf(v4.z); vs[3]=f2bf(v4.w);
    *(s16x4*)&vt[r * 68 + c4] = vs;
  }
  __syncthreads();
  const size_t obase = ((size_t)((b * H + h) * NT + tile)) * 4096;
  #pragma unroll
  for (int j = 0; j < 2; ++j) {          // K frags
    int f = w + j * 4, kk = f >> 2, mf = f & 3;
    int row = mf * 16 + lm, col = kk * 32 + lg * 4;
    s16x4 c0 = *(const s16x4*)&kt[row * 68 + col];
    s16x4 c1 = *(const s16x4*)&kt[row * 68 + col + 16];
    bf16x8 a;
    a[0]=c0[0]; a[1]=c0[1]; a[2]=c0[2]; a[3]=c0[3];
    a[4]=c1[0]; a[5]=c1[1]; a[6]=c1[2]; a[7]=c1[3];
    *(bf16x8*)&Kb[obase + (size_t)(f * 64 + lane) * 8] = a;
  }
  #pragma unroll
  for (int j = 0; j < 2; ++j) {          // V^T frags
    int f = w + j * 4, kk = f >> 2, of = f & 3;
    int col = of * 16 + lm;
    bf16x8 a;
    #pragma unroll
    for (int half = 0; half < 2; ++half)
      #pragma unroll
      for (int e = 0; e < 4; ++e)
        a[half * 4 + e] = vt[(kk * 32 + lg * 4 + half * 16 + e) * 68 + col];
    *(bf16x8*)&Vb[obase + (size_t)(f * 64 + lane) * 8] = a;
  }
}

// ---------------------------------------------------------------------------
// Flash attention: 2-wave blocks, 32 queries per wave (2 q-frags), counted
// vmcnt, bias distance-2 register double-buffer, T13 skip-rescale.
// ---------------------------------------------------------------------------
__device__ __forceinline__ void attn_tile(const short* kb, const short* vb,
                                          const f32x4 (&br)[2][4],
                                          const bf16x8 (&qf)[2][2],
                                          int lane, float* M, float* L,
                                          f32x4 (&o)[2][4]) {
  const f32x4 zero4 = {0.f, 0.f, 0.f, 0.f};
  f32x4 sacc[2][4];
  #pragma unroll
  for (int fq = 0; fq < 2; ++fq)
    #pragma unroll
    for (int i = 0; i < 4; ++i) sacc[fq][i] = zero4;
  __builtin_amdgcn_s_setprio(1);
  #pragma unroll
  for (int kk = 0; kk < 2; ++kk)
    #pragma unroll
    for (int mf = 0; mf < 4; ++mf) {
      bf16x8 a = *(const bf16x8*)&kb[(kk * 4 + mf) * 512 + lane * 8];
      sacc[0][mf] = MFMA_BF16(a, qf[0][kk], sacc[0][mf], 0, 0, 0);
      sacc[1][mf] = MFMA_BF16(a, qf[1][kk], sacc[1][mf], 0, 0, 0);
    }
  __builtin_amdgcn_s_setprio(0);
  float p[2][4][4];
  float tmax[2] = {-__builtin_inff(), -__builtin_inff()};
  #pragma unroll
  for (int fq = 0; fq < 2; ++fq)
    #pragma unroll
    for (int mf = 0; mf < 4; ++mf)
      #pragma unroll
      for (int j = 0; j < 4; ++j) {
        float tv = (sacc[fq][mf][j] + br[fq][mf][j]) * SL;
        p[fq][mf][j] = tv;
        tmax[fq] = fmaxf(tmax[fq], tv);
      }
  #pragma unroll
  for (int fq = 0; fq < 2; ++fq) {
    tmax[fq] = fmaxf(tmax[fq], __shfl_xor(tmax[fq], 16, 64));
    tmax[fq] = fmaxf(tmax[fq], __shfl_xor(tmax[fq], 32, 64));
  }
  const int skip = (tmax[0] <= M[0]) && (tmax[1] <= M[1]);
  if (!__all(skip)) {
    #pragma unroll
    for (int fq = 0; fq < 2; ++fq) {
      float Mn = fmaxf(M[fq], tmax[fq]);
      float alpha = exp2f(M[fq] - Mn);
      #pragma unroll
      for (int of = 0; of < 4; ++of) {
        o[fq][of][0] *= alpha; o[fq][of][1] *= alpha;
        o[fq][of][2] *= alpha; o[fq][of][3] *= alpha;
      }
      L[fq] *= alpha;
      M[fq] = Mn;
    }
  }
  #pragma unroll
  for (int fq = 0; fq < 2; ++fq) {
    float psum = 0.f;
    #pragma unroll
    for (int mf = 0; mf < 4; ++mf)
      #pragma unroll
      for (int j = 0; j < 4; ++j) {
        float e = exp2f(p[fq][mf][j] - M[fq]);
        p[fq][mf][j] = e;
        psum += e;
      }
    psum += __shfl_xor(psum, 16, 64);
    psum += __shfl_xor(psum, 32, 64);
    L[fq] += psum;
  }
  bf16x8 pb[2][2];
  #pragma unroll
  for (int fq = 0; fq < 2; ++fq)
    #pragma unroll
    for (int kk = 0; kk < 2; ++kk)
      #pragma unroll
      for (int j = 0; j < 8; ++j)
        pb[fq][kk][j] = f2bf(p[fq][kk * 2 + (j >> 2)][j & 3]);
  __builtin_amdgcn_s_setprio(1);
  #pragma unroll
  for (int kk = 0; kk < 2; ++kk)
    #pragma unroll
    for (int of = 0; of < 4; ++of) {
      bf16x8 a = *(const bf16x8*)&vb[(kk * 4 + of) * 512 + lane * 8];
      o[0][of] = MFMA_BF16(a, pb[0][kk], o[0][of], 0, 0, 0);
      o[1][of] = MFMA_BF16(a, pb[1][kk], o[1][of], 0, 0, 0);
    }
  __builtin_amdgcn_s_setprio(0);
}

__global__ __launch_bounds__(128, 2)
void attn_fused(const float* __restrict__ Qg, const float* __restrict__ Bg,
                const short* __restrict__ Kb, const short* __restrict__ Vb,
                short* __restrict__ comb) {
  __shared__ __attribute__((aligned(16))) short smem[16384]; // buf0: K@0 V@4096; buf1: K@8192 V@12288
  const int bid = blockIdx.x;
  // XCD c = bid&7. b-pair (x>>3) shares bias tile in L2; h = rr>>2 groups
  // same-(b,h) K/V on one XCD across 4 consecutive rounds.
  const int x = bid & 15, rr = bid >> 4;
  const int c = x & 7, b = x >> 3;
  const int h = rr >> 2, qt = (rr & 3) * 8 + c;
  const int q0 = qt * 64;
  const int t = threadIdx.x, lane = t & 63, w = t >> 6;   // w in {0,1}
  const int lg = lane >> 4, lm = lane & 15;

  // Q frags: qfrag fq covers query col q = q0 + w*32 + fq*16 + lm
  bf16x8 qf[2][2];
  #pragma unroll
  for (int fq = 0; fq < 2; ++fq) {
    const float* qp = Qg + ((size_t)(b * S + q0 + w * 32 + fq * 16 + lm)) * D + h * HD;
    #pragma unroll
    for (int kk = 0; kk < 2; ++kk)
      #pragma unroll
      for (int j = 0; j < 8; ++j)
        qf[fq][kk][j] = f2bf(qp[kk * 32 + (j >> 2) * 16 + lg * 4 + (j & 3)]);
  }

  const short* Kt = Kb + ((size_t)(b * H + h) * NT) * 4096;
  const short* Vt = Vb + ((size_t)(b * H + h) * NT) * 4096;
  const float* bp = Bg + ((size_t)(h * S + q0 + w * 32 + lm)) * S + lg * 4;

  const f32x4 zero4 = {0.f, 0.f, 0.f, 0.f};
  f32x4 o[2][4];
  #pragma unroll
  for (int fq = 0; fq < 2; ++fq)
    #pragma unroll
    for (int i = 0; i < 4; ++i) o[fq][i] = zero4;
  float M[2] = {-__builtin_inff(), -__builtin_inff()};
  float L[2] = {0.f, 0.f};

  // wave w stages K/V frags [w*4, w*4+4): 8 gload_lds per wave per tile
#define STAGE(tile, buf)                                                \
  {                                                                     \
    const short* kg_ = Kt + (size_t)(tile) * 4096;                      \
    const short* vg_ = Vt + (size_t)(tile) * 4096;                      \
    _Pragma("unroll")                                                   \
    for (int f_ = 0; f_ < 4; ++f_) {                                    \
      int fr_ = w * 4 + f_;                                             \
      GLDS16(kg_ + (size_t)(fr_ * 64 + lane) * 8, (buf) + fr_ * 512);   \
      GLDS16(vg_ + (size_t)(fr_ * 64 + lane) * 8, (buf) + 4096 + fr_ * 512); \
    }                                                                   \
  }

  // 8 dwordx4 per lane: rows (2 q-frags), cols mf*16 + lg*4 within kv tile
#define BLOAD(dst, tile)                                                \
  {                                                                     \
    _Pragma("unroll")                                                   \
    for (int fq_ = 0; fq_ < 2; ++fq_)                                   \
      _Pragma("unroll")                                                 \
      for (int mf_ = 0; mf_ < 4; ++mf_)                                 \
        dst[fq_][mf_] = *(const f32x4*)(bp + (size_t)fq_ * 16 * S +     \
                                        (size_t)(tile) * 64 + mf_ * 16); \
  }

  f32x4 biasA[2][4], biasB[2][4];
  BLOAD(biasA, 0);            // 8 vm
  STAGE(0, smem);             // 8 vm
  BLOAD(biasB, 1);            // 8 vm

  // steady state per half-iter: issue STAGE(t+1)=8, later BLOAD(t+2)=8.
  // WAITV(16) leaves {bias(t+1), KV(t+1)} in flight, retires bias(t)+KV(t).
  for (int tt = 0; tt < NT; tt += 2) {
    SBAR();
    STAGE(tt + 1, smem + 8192);
    WAITV(16);
    SBAR();
    attn_tile(smem, smem + 4096, biasA, qf, lane, M, L, o);
    { int bt = (tt + 2 < NT) ? tt + 2 : 0; BLOAD(biasA, bt); }
    SBAR();
    { int st = (tt + 2 < NT) ? tt + 2 : 0; STAGE(st, smem); }
    WAITV(16);
    SBAR();
    attn_tile(smem + 8192, smem + 12288, biasB, qf, lane, M, L, o);
    { int bt = (tt + 3 < NT) ? tt + 3 : 1; BLOAD(biasB, bt); }
  }

  // normalize, transpose O^T -> [q][d] via LDS, coalesced bf16 store
  const float iL0 = 1.f / L[0], iL1 = 1.f / L[1];
  __syncthreads();                       // drains vmcnt + barrier: smem reusable
  short* out_lds = smem;                 // [64 q][64 d], stride 72
  #pragma unroll
  for (int fq = 0; fq < 2; ++fq)
    #pragma unroll
    for (int of = 0; of < 4; ++of)
      #pragma unroll
      for (int j = 0; j < 4; ++j)
        out_lds[(w * 32 + fq * 16 + lm) * 72 + of * 16 + lg * 4 + j] =
            f2bf(o[fq][of][j] * (fq ? iL1 : iL0));
  __syncthreads();
  #pragma unroll
  for (int it = 0; it < 4; ++it) {
    int idx = it * 128 + t;
    int r = idx >> 3, seg = idx & 7;
    u32x4 u = *(const u32x4*)&out_lds[r * 72 + seg * 8];
    *(u32x4*)&comb[((size_t)(b * S + q0 + r)) * D + h * HD + seg * 8] = u;
  }
#undef STAGE
#undef BLOAD
}

// ---------------------------------------------------------------------------
// w_out [k][n] f32 -> Wt [n][k] bf16
// ---------------------------------------------------------------------------
__global__ __launch_bounds__(256)
void wt_kernel(const float* __restrict__ W, short* __restrict__ Wt) {
  __shared__ __attribute__((aligned(16))) short tile[64 * 72];
  const int n0 = blockIdx.x * 64, k0 = blockIdx.y * 64;
  const int t = threadIdx.x;
  #pragma unroll
  for (int i = 0; i < 4; ++i) {
    int idx = i * 256 + t;
    int r  = idx >> 4, c4 = (idx & 15) * 4;
    float4 wv = *(const float4*)(W + (size_t)(k0 + r) * D + n0 + c4);
    tile[(c4 + 0) * 72 + r] = f2bf(wv.x);
    tile[(c4 + 1) * 72 + r] = f2bf(wv.y);
    tile[(c4 + 2) * 72 + r] = f2bf(wv.z);
    tile[(c4 + 3) * 72 + r] = f2bf(wv.w);
  }
  __syncthreads();
  #pragma unroll
  for (int it = 0; it < 2; ++it) {
    int idx = it * 256 + t;
    int r = idx >> 3, seg = idx & 7;
    u32x4 u = *(const u32x4*)&tile[r * 72 + seg * 8];
    *(u32x4*)&Wt[(size_t)(n0 + r) * D + k0 + seg * 8] = u;
  }
}

// ---------------------------------------------------------------------------
// proj: C[4096,1024] f32 = A bf16 * Wt^T. 128x64 tile, counted-vmcnt,
// both-sides 16B-unit XOR swizzle on LDS.
// ---------------------------------------------------------------------------
__device__ __forceinline__ bf16x8 ld_frag_swz(const short* base, int row, int kk, int lg) {
  const char* rp = (const char*)base + row * 128 + (lg & 1) * 8;
  int u0 = kk * 4 + (lg >> 1);
  int f  = row & 7;
  s16x4 c0 = *(const s16x4*)(rp + ((u0 ^ f) << 4));
  s16x4 c1 = *(const s16x4*)(rp + (((u0 + 2) ^ f) << 4));
  bf16x8 a;
  a[0]=c0[0]; a[1]=c0[1]; a[2]=c0[2]; a[3]=c0[3];
  a[4]=c1[0]; a[5]=c1[1]; a[6]=c1[2]; a[7]=c1[3];
  return a;
}

__global__ __launch_bounds__(256, 2)
void proj_gemm(const short* __restrict__ A, const short* __restrict__ Bt,
               float* __restrict__ C) {
  __shared__ __attribute__((aligned(16))) short a_lds[2][8192];
  __shared__ __attribute__((aligned(16))) short b_lds[2][4096];
  const int m0 = blockIdx.x * 128, n0 = blockIdx.y * 64;
  const int t = threadIdx.x, lane = t & 63, w = t >> 6;
  const int lg = lane >> 4, lm = lane & 15;
  const int srow = lane >> 3;
  const int sunit = (lane & 7) ^ srow;

  const f32x4 zero4 = {0.f, 0.f, 0.f, 0.f};
  f32x4 acc[2][4];
  #pragma unroll
  for (int i = 0; i < 2; ++i)
    #pragma unroll
    for (int j = 0; j < 4; ++j) acc[i][j] = zero4;

#define PSTAGE(ks, ab, bb)                                                  \
  {                                                                         \
    const short* ag_ = A  + (size_t)m0 * D + (ks) * 64;                     \
    const short* bg_ = Bt + (size_t)n0 * D + (ks) * 64;                     \
    _Pragma("unroll")                                                       \
    for (int i_ = 0; i_ < 4; ++i_) {                                        \
      int j_ = w * 4 + i_;                                                  \
      GLDS16(ag_ + (size_t)(j_ * 8 + srow) * D + sunit * 8, (ab) + j_ * 512); \
    }                                                                       \
    _Pragma("unroll")                                                       \
    for (int i_ = 0; i_ < 2; ++i_) {                                        \
      int j_ = w * 2 + i_;                                                  \
      GLDS16(bg_ + (size_t)(j_ * 8 + srow) * D + sunit * 8, (bb) + j_ * 512); \
    }                                                                       \
  }

#define PCOMPUTE(ab, bb)                                                    \
  {                                                                         \
    _Pragma("unroll")                                                       \
    for (int kk = 0; kk < 2; ++kk) {                                        \
      bf16x8 af0 = ld_frag_swz(ab, w * 32 + lm, kk, lg);                    \
      bf16x8 af1 = ld_frag_swz(ab, w * 32 + 16 + lm, kk, lg);               \
      bf16x8 bf0 = ld_frag_swz(bb, lm, kk, lg);                             \
      bf16x8 bf1 = ld_frag_swz(bb, 16 + lm, kk, lg);                        \
      bf16x8 bf2 = ld_frag_swz(bb, 32 + lm, kk, lg);                        \
      bf16x8 bf3 = ld_frag_swz(bb, 48 + lm, kk, lg);                        \
      __builtin_amdgcn_s_setprio(1);                                        \
      acc[0][0] = MFMA_BF16(af0, bf0, acc[0][0], 0, 0, 0);                  \
      acc[0][1] = MFMA_BF16(af0, bf1, acc[0][1], 0, 0, 0);                  \
      acc[0][2] = MFMA_BF16(af0, bf2, acc[0][2], 0, 0, 0);                  \
      acc[0][3] = MFMA_BF16(af0, bf3, acc[0][3], 0, 0, 0);                  \
      acc[1][0] = MFMA_BF16(af1, bf0, acc[1][0], 0, 0, 0);                  \
      acc[1][1] = MFMA_BF16(af1, bf1, acc[1][1], 0, 0, 0);                  \
      acc[1][2] = MFMA_BF16(af1, bf2, acc[1][2], 0, 0, 0);                  \
      acc[1][3] = MFMA_BF16(af1, bf3, acc[1][3], 0, 0, 0);                  \
      __builtin_amdgcn_s_setprio(0);                                        \
    }                                                                       \
  }

  PSTAGE(0, a_lds[0], b_lds[0]);
  for (int ks = 0; ks < 16; ks += 2) {
    SBAR();
    PSTAGE(ks + 1, a_lds[1], b_lds[1]);
    WAITV(6);
    SBAR();
    PCOMPUTE(a_lds[0], b_lds[0]);
    SBAR();
    if (ks + 2 < 16) {
      PSTAGE(ks + 2, a_lds[0], b_lds[0]);
      WAITV(6);
    } else {
      WAITV(0);
    }
    SBAR();
    PCOMPUTE(a_lds[1], b_lds[1]);
  }

  #pragma unroll
  for (int mf = 0; mf < 2; ++mf)
    #pragma unroll
    for (int j = 0; j < 4; ++j)
      #pragma unroll
      for (int nf = 0; nf < 4; ++nf)
        C[(size_t)(m0 + w * 32 + mf * 16 + lg * 4 + j) * D +
          n0 + nf * 16 + lm] = acc[mf][nf][j];
#undef PSTAGE
#undef PCOMPUTE
}

extern "C" void kernel_launch(void* const* d_in, const int* in_sizes, int n_in,
                              void* d_out, int out_size, void* d_ws, size_t ws_size,
                              hipStream_t stream) {
  const float* Qg = (const float*)d_in[0];
  const float* Kg = (const float*)d_in[1];
  const float* Vg = (const float*)d_in[2];
  const float* Bg = (const float*)d_in[3];
  const float* Wg = (const float*)d_in[4];
  float* out = (float*)d_out;

  short* comb = (short*)d_ws;                          //  8 MB bf16 [4096][1024]
  short* Wt   = comb + (size_t)(2 * S) * D;            //  2 MB bf16 [1024][1024]
  short* Kb   = Wt   + (size_t)D * D;                  //  8 MB fragment-major K
  short* Vb   = Kb   + (size_t)2 * H * NT * 4096;      //  8 MB fragment-major V^T

  kv_prep<<<dim3(NT, H, 2), 256, 0, stream>>>(Kg, Vg, Kb, Vb);
  wt_kernel<<<dim3(D / 64, D / 64), 256, 0, stream>>>(Wg, Wt);
  attn_fused<<<dim3(1024), 128, 0, stream>>>(Qg, Bg, Kb, Vb, comb);
  proj_gemm<<<dim3(32, 16), 256, 0, stream>>>(comb, Wt, out);
}

// Round 5
// 154.088 us; speedup vs baseline: 1.0048x; 1.0048x over previous
//
#include <hip/hip_runtime.h>

typedef float  f32x4  __attribute__((ext_vector_type(4)));
typedef short  bf16x8 __attribute__((ext_vector_type(8)));
typedef short  s16x4  __attribute__((ext_vector_type(4)));
typedef unsigned int u32x4 __attribute__((ext_vector_type(4)));

#define MFMA_BF16 __builtin_amdgcn_mfma_f32_16x16x32_bf16

__device__ __forceinline__ short f2bf(float f) {
  __bf16 h = (__bf16)f;
  return __builtin_bit_cast(short, h);
}

constexpr int S = 2048, D = 1024, H = 16, HD = 64;
constexpr int NT = S / 64;                 // 32 kv tiles
constexpr float SCALE = 0.125f;            // 1/sqrt(64)
constexpr float L2E = 1.44269504f;
constexpr float SL = SCALE * L2E;          // logits -> log2 domain in one mul

#define GLDS16(g, l) __builtin_amdgcn_global_load_lds( \
    (const __attribute__((address_space(1))) unsigned*)(g), \
    (__attribute__((address_space(3))) unsigned*)(l), 16, 0, 0)

#define WAITV(n) asm volatile("s_waitcnt vmcnt(" #n ")" ::: "memory")
#define SBAR()   __builtin_amdgcn_s_barrier()

// ---------------------------------------------------------------------------
// K/V prep: f32 [B,S,D] head-slices -> interleaved bf16 fragment-major tiles.
// Per (b,h,kv-tile): 16 frags of 512 shorts (1KB): f<8 = K frag (kk*4+mf),
// f>=8 = V^T frag (kk*4+of). Tile block = 8192 shorts (16KB).
// ---------------------------------------------------------------------------
__global__ __launch_bounds__(256)
void kv_prep(const float* __restrict__ Kg, const float* __restrict__ Vg,
             short* __restrict__ KVb) {
  const int tile = blockIdx.x, h = blockIdx.y, b = blockIdx.z;
  const int t = threadIdx.x, lane = t & 63, w = t >> 6;
  const int lg = lane >> 4, lm = lane & 15;
  __shared__ short kt[64 * 68], vt[64 * 68];
  const float* kp = Kg + ((size_t)(b * S + tile * 64)) * D + h * HD;
  const float* vp = Vg + ((size_t)(b * S + tile * 64)) * D + h * HD;
  #pragma unroll
  for (int i = 0; i < 4; ++i) {
    int idx = i * 256 + t, r = idx >> 4, c4 = (idx & 15) * 4;
    float4 k4 = *(const float4*)(kp + (size_t)r * D + c4);
    s16x4 ks; ks[0]=f2bf(k4.x); ks[1]=f2bf(k4.y); ks[2]=f2bf(k4.z); ks[3]=f2bf(k4.w);
    *(s16x4*)&kt[r * 68 + c4] = ks;
    float4 v4 = *(const float4*)(vp + (size_t)r * D + c4);
    s16x4 vs; vs[0]=f2bf(v4.x); vs[1]=f2bf(v4.y); vs[2]=f2bf(v4.z); vs[3]=f2bf(v4.w);
    *(s16x4*)&vt[r * 68 + c4] = vs;
  }
  __syncthreads();
  const size_t obase = ((size_t)((b * H + h) * NT + tile)) * 8192;
  #pragma unroll
  for (int j = 0; j < 2; ++j) {          // K frags f = kk*4+mf
    int f = w + j * 4, kk = f >> 2, mf = f & 3;
    int row = mf * 16 + lm, col = kk * 32 + lg * 4;
    s16x4 c0 = *(const s16x4*)&kt[row * 68 + col];
    s16x4 c1 = *(const s16x4*)&kt[row * 68 + col + 16];
    bf16x8 a;
    a[0]=c0[0]; a[1]=c0[1]; a[2]=c0[2]; a[3]=c0[3];
    a[4]=c1[0]; a[5]=c1[1]; a[6]=c1[2]; a[7]=c1[3];
    *(bf16x8*)&KVb[obase + (size_t)(f * 64 + lane) * 8] = a;
  }
  #pragma unroll
  for (int j = 0; j < 2; ++j) {          // V^T frags f = 8 + kk*4+of
    int fv = w + j * 4, kk = fv >> 2, of = fv & 3;
    int col = of * 16 + lm;
    bf16x8 a;
    #pragma unroll
    for (int half = 0; half < 2; ++half)
      #pragma unroll
      for (int e = 0; e < 4; ++e)
        a[half * 4 + e] = vt[(kk * 32 + lg * 4 + half * 16 + e) * 68 + col];
    *(bf16x8*)&KVb[obase + (size_t)((8 + fv) * 64 + lane) * 8] = a;
  }
}

// ---------------------------------------------------------------------------
// Flash attention: 4-wave blocks, 16 queries/wave, counted vmcnt, depth-2
// register bias double-buffer, skip-rescale.
// ---------------------------------------------------------------------------
__device__ __forceinline__ void attn_tile(const short* buf, const f32x4 (&br)[4],
                                          const bf16x8 (&qf)[2],
                                          int lane, float& M, float& L,
                                          f32x4 (&o)[4]) {
  const short* kb = buf;
  const short* vb = buf + 4096;
  const f32x4 zero4 = {0.f, 0.f, 0.f, 0.f};
  f32x4 sacc[4];
  #pragma unroll
  for (int i = 0; i < 4; ++i) sacc[i] = zero4;
  __builtin_amdgcn_s_setprio(1);
  #pragma unroll
  for (int kk = 0; kk < 2; ++kk)
    #pragma unroll
    for (int mf = 0; mf < 4; ++mf) {
      bf16x8 a = *(const bf16x8*)&kb[(kk * 4 + mf) * 512 + lane * 8];
      sacc[mf] = MFMA_BF16(a, qf[kk], sacc[mf], 0, 0, 0);
    }
  __builtin_amdgcn_s_setprio(0);
  float p[4][4];
  float tmax = -__builtin_inff();
  #pragma unroll
  for (int mf = 0; mf < 4; ++mf)
    #pragma unroll
    for (int j = 0; j < 4; ++j) {
      float tv = (sacc[mf][j] + br[mf][j]) * SL;
      p[mf][j] = tv;
      tmax = fmaxf(tmax, tv);
    }
  tmax = fmaxf(tmax, __shfl_xor(tmax, 16, 64));
  tmax = fmaxf(tmax, __shfl_xor(tmax, 32, 64));
  if (!__all(tmax <= M)) {
    float Mn = fmaxf(M, tmax);
    float alpha = exp2f(M - Mn);
    #pragma unroll
    for (int of = 0; of < 4; ++of) {
      o[of][0] *= alpha; o[of][1] *= alpha;
      o[of][2] *= alpha; o[of][3] *= alpha;
    }
    L *= alpha;
    M = Mn;
  }
  float psum = 0.f;
  #pragma unroll
  for (int mf = 0; mf < 4; ++mf)
    #pragma unroll
    for (int j = 0; j < 4; ++j) {
      float e = exp2f(p[mf][j] - M);
      p[mf][j] = e;
      psum += e;
    }
  psum += __shfl_xor(psum, 16, 64);
  psum += __shfl_xor(psum, 32, 64);
  L += psum;
  bf16x8 pb[2];
  #pragma unroll
  for (int kk = 0; kk < 2; ++kk)
    #pragma unroll
    for (int j = 0; j < 8; ++j)
      pb[kk][j] = f2bf(p[kk * 2 + (j >> 2)][j & 3]);
  __builtin_amdgcn_s_setprio(1);
  #pragma unroll
  for (int kk = 0; kk < 2; ++kk)
    #pragma unroll
    for (int of = 0; of < 4; ++of) {
      bf16x8 a = *(const bf16x8*)&vb[(kk * 4 + of) * 512 + lane * 8];
      o[of] = MFMA_BF16(a, pb[kk], o[of], 0, 0, 0);
    }
  __builtin_amdgcn_s_setprio(0);
}

__global__ __launch_bounds__(256, 4)
void attn_fused(const float* __restrict__ Qg, const float* __restrict__ Bg,
                const short* __restrict__ KVb, short* __restrict__ comb) {
  __shared__ __attribute__((aligned(16))) short smem[16384]; // buf0 @0, buf1 @8192 (16KB each)
  const int bid = blockIdx.x;
  // XCD c = bid&7 hosts h in {2c, 2c+1} x both b: K/V ~2MB L2-resident per
  // XCD; b-pairs (slots bid, bid+256) share bias tiles in L2.
  const int c = bid & 7, g = bid >> 3;
  const int qt = g & 31, z = g >> 5;
  const int b = z & 1, h = 2 * c + (z >> 1);
  const int q0 = qt * 64;
  const int t = threadIdx.x, lane = t & 63, w = t >> 6;
  const int lg = lane >> 4, lm = lane & 15;

  // Q fragment: lane's query col = q0 + w*16 + lm
  bf16x8 qf[2];
  {
    const float* qp = Qg + ((size_t)(b * S + q0 + w * 16 + lm)) * D + h * HD;
    #pragma unroll
    for (int kk = 0; kk < 2; ++kk)
      #pragma unroll
      for (int j = 0; j < 8; ++j)
        qf[kk][j] = f2bf(qp[kk * 32 + (j >> 2) * 16 + lg * 4 + (j & 3)]);
  }

  const short* KVt = KVb + ((size_t)(b * H + h) * NT) * 8192;
  const float* bp = Bg + ((size_t)(h * S + q0 + w * 16 + lm)) * S + lg * 4;

  const f32x4 zero4 = {0.f, 0.f, 0.f, 0.f};
  f32x4 o[4];
  #pragma unroll
  for (int i = 0; i < 4; ++i) o[i] = zero4;
  float M = -__builtin_inff(), L = 0.f;

  // wave w stages frags [w*4, w*4+4) of the 16-frag interleaved tile: 4 vm
#define STAGE(tile, buf)                                                \
  {                                                                     \
    const short* kvg_ = KVt + (size_t)(tile) * 8192;                    \
    _Pragma("unroll")                                                   \
    for (int f_ = 0; f_ < 4; ++f_) {                                    \
      int fr_ = w * 4 + f_;                                             \
      GLDS16(kvg_ + (size_t)(fr_ * 64 + lane) * 8, (buf) + fr_ * 512);  \
    }                                                                   \
  }

  // 4 dwordx4 per lane: row = own q, cols mf*16 + lg*4
#define BLOAD(dst, tile)                                                \
  {                                                                     \
    _Pragma("unroll")                                                   \
    for (int mf_ = 0; mf_ < 4; ++mf_)                                   \
      dst[mf_] = *(const f32x4*)(bp + (size_t)(tile) * 64 + mf_ * 16);  \
  }

  f32x4 biasA[4], biasB[4];
  BLOAD(biasA, 0);            // 4 vm
  STAGE(0, smem);             // 4 vm
  BLOAD(biasB, 1);            // 4 vm

  // steady state: WAITV(8) leaves newest {bias(t+1)4, KV(t+1)4} in flight,
  // retires bias(t)+KV(t).
  for (int tt = 0; tt < NT; tt += 2) {
    SBAR();
    STAGE(tt + 1, smem + 8192);
    WAITV(8);
    SBAR();
    attn_tile(smem, biasA, qf, lane, M, L, o);
    { int bt = (tt + 2 < NT) ? tt + 2 : 0; BLOAD(biasA, bt); }
    SBAR();
    { int st = (tt + 2 < NT) ? tt + 2 : 0; STAGE(st, smem); }
    WAITV(8);
    SBAR();
    attn_tile(smem + 8192, biasB, qf, lane, M, L, o);
    { int bt = (tt + 3 < NT) ? tt + 3 : 1; BLOAD(biasB, bt); }
  }

  // normalize, transpose O^T -> [q][d] via LDS, coalesced bf16 store
  const float invL = 1.f / L;
  __syncthreads();                       // drains vmcnt; smem reusable
  short* out_lds = smem;                 // [64 q][64 d], stride 72 (16B rows)
  #pragma unroll
  for (int of = 0; of < 4; ++of)
    #pragma unroll
    for (int j = 0; j < 4; ++j)
      out_lds[(w * 16 + lm) * 72 + of * 16 + lg * 4 + j] = f2bf(o[of][j] * invL);
  __syncthreads();
  #pragma unroll
  for (int it = 0; it < 2; ++it) {
    int idx = it * 256 + t;
    int r = idx >> 3, seg = idx & 7;
    u32x4 u = *(const u32x4*)&out_lds[r * 72 + seg * 8];
    *(u32x4*)&comb[((size_t)(b * S + q0 + r)) * D + h * HD + seg * 8] = u;
  }
#undef STAGE
#undef BLOAD
}

// ---------------------------------------------------------------------------
// w_out [k][n] f32 -> Wt [n][k] bf16
// ---------------------------------------------------------------------------
__global__ __launch_bounds__(256)
void wt_kernel(const float* __restrict__ W, short* __restrict__ Wt) {
  __shared__ __attribute__((aligned(16))) short tile[64 * 72];
  const int n0 = blockIdx.x * 64, k0 = blockIdx.y * 64;
  const int t = threadIdx.x;
  #pragma unroll
  for (int i = 0; i < 4; ++i) {
    int idx = i * 256 + t;
    int r  = idx >> 4, c4 = (idx & 15) * 4;
    float4 wv = *(const float4*)(W + (size_t)(k0 + r) * D + n0 + c4);
    tile[(c4 + 0) * 72 + r] = f2bf(wv.x);
    tile[(c4 + 1) * 72 + r] = f2bf(wv.y);
    tile[(c4 + 2) * 72 + r] = f2bf(wv.z);
    tile[(c4 + 3) * 72 + r] = f2bf(wv.w);
  }
  __syncthreads();
  #pragma unroll
  for (int it = 0; it < 2; ++it) {
    int idx = it * 256 + t;
    int r = idx >> 3, seg = idx & 7;
    u32x4 u = *(const u32x4*)&tile[r * 72 + seg * 8];
    *(u32x4*)&Wt[(size_t)(n0 + r) * D + k0 + seg * 8] = u;
  }
}

// ---------------------------------------------------------------------------
// proj: C[4096,1024] f32 = A bf16 * Wt^T. 128x64 tile, counted-vmcnt,
// both-sides 16B-unit XOR swizzle on LDS.
// ---------------------------------------------------------------------------
__device__ __forceinline__ bf16x8 ld_frag_swz(const short* base, int row, int kk, int lg) {
  const char* rp = (const char*)base + row * 128 + (lg & 1) * 8;
  int u0 = kk * 4 + (lg >> 1);
  int f  = row & 7;
  s16x4 c0 = *(const s16x4*)(rp + ((u0 ^ f) << 4));
  s16x4 c1 = *(const s16x4*)(rp + (((u0 + 2) ^ f) << 4));
  bf16x8 a;
  a[0]=c0[0]; a[1]=c0[1]; a[2]=c0[2]; a[3]=c0[3];
  a[4]=c1[0]; a[5]=c1[1]; a[6]=c1[2]; a[7]=c1[3];
  return a;
}

__global__ __launch_bounds__(256, 2)
void proj_gemm(const short* __restrict__ A, const short* __restrict__ Bt,
               float* __restrict__ C) {
  __shared__ __attribute__((aligned(16))) short a_lds[2][8192];
  __shared__ __attribute__((aligned(16))) short b_lds[2][4096];
  const int m0 = blockIdx.x * 128, n0 = blockIdx.y * 64;
  const int t = threadIdx.x, lane = t & 63, w = t >> 6;
  const int lg = lane >> 4, lm = lane & 15;
  const int srow = lane >> 3;
  const int sunit = (lane & 7) ^ srow;

  const f32x4 zero4 = {0.f, 0.f, 0.f, 0.f};
  f32x4 acc[2][4];
  #pragma unroll
  for (int i = 0; i < 2; ++i)
    #pragma unroll
    for (int j = 0; j < 4; ++j) acc[i][j] = zero4;

#define PSTAGE(ks, ab, bb)                                                  \
  {                                                                         \
    const short* ag_ = A  + (size_t)m0 * D + (ks) * 64;                     \
    const short* bg_ = Bt + (size_t)n0 * D + (ks) * 64;                     \
    _Pragma("unroll")                                                       \
    for (int i_ = 0; i_ < 4; ++i_) {                                        \
      int j_ = w * 4 + i_;                                                  \
      GLDS16(ag_ + (size_t)(j_ * 8 + srow) * D + sunit * 8, (ab) + j_ * 512); \
    }                                                                       \
    _Pragma("unroll")                                                       \
    for (int i_ = 0; i_ < 2; ++i_) {                                        \
      int j_ = w * 2 + i_;                                                  \
      GLDS16(bg_ + (size_t)(j_ * 8 + srow) * D + sunit * 8, (bb) + j_ * 512); \
    }                                                                       \
  }

#define PCOMPUTE(ab, bb)                                                    \
  {                                                                         \
    _Pragma("unroll")                                                       \
    for (int kk = 0; kk < 2; ++kk) {                                        \
      bf16x8 af0 = ld_frag_swz(ab, w * 32 + lm, kk, lg);                    \
      bf16x8 af1 = ld_frag_swz(ab, w * 32 + 16 + lm, kk, lg);               \
      bf16x8 bf0 = ld_frag_swz(bb, lm, kk, lg);                             \
      bf16x8 bf1 = ld_frag_swz(bb, 16 + lm, kk, lg);                        \
      bf16x8 bf2 = ld_frag_swz(bb, 32 + lm, kk, lg);                        \
      bf16x8 bf3 = ld_frag_swz(bb, 48 + lm, kk, lg);                        \
      __builtin_amdgcn_s_setprio(1);                                        \
      acc[0][0] = MFMA_BF16(af0, bf0, acc[0][0], 0, 0, 0);                  \
      acc[0][1] = MFMA_BF16(af0, bf1, acc[0][1], 0, 0, 0);                  \
      acc[0][2] = MFMA_BF16(af0, bf2, acc[0][2], 0, 0, 0);                  \
      acc[0][3] = MFMA_BF16(af0, bf3, acc[0][3], 0, 0, 0);                  \
      acc[1][0] = MFMA_BF16(af1, bf0, acc[1][0], 0, 0, 0);                  \
      acc[1][1] = MFMA_BF16(af1, bf1, acc[1][1], 0, 0, 0);                  \
      acc[1][2] = MFMA_BF16(af1, bf2, acc[1][2], 0, 0, 0);                  \
      acc[1][3] = MFMA_BF16(af1, bf3, acc[1][3], 0, 0, 0);                  \
      __builtin_amdgcn_s_setprio(0);                                        \
    }                                                                       \
  }

  PSTAGE(0, a_lds[0], b_lds[0]);
  for (int ks = 0; ks < 16; ks += 2) {
    SBAR();
    PSTAGE(ks + 1, a_lds[1], b_lds[1]);
    WAITV(6);
    SBAR();
    PCOMPUTE(a_lds[0], b_lds[0]);
    SBAR();
    if (ks + 2 < 16) {
      PSTAGE(ks + 2, a_lds[0], b_lds[0]);
      WAITV(6);
    } else {
      WAITV(0);
    }
    SBAR();
    PCOMPUTE(a_lds[1], b_lds[1]);
  }

  #pragma unroll
  for (int mf = 0; mf < 2; ++mf)
    #pragma unroll
    for (int j = 0; j < 4; ++j)
      #pragma unroll
      for (int nf = 0; nf < 4; ++nf)
        C[(size_t)(m0 + w * 32 + mf * 16 + lg * 4 + j) * D +
          n0 + nf * 16 + lm] = acc[mf][nf][j];
#undef PSTAGE
#undef PCOMPUTE
}

extern "C" void kernel_launch(void* const* d_in, const int* in_sizes, int n_in,
                              void* d_out, int out_size, void* d_ws, size_t ws_size,
                              hipStream_t stream) {
  const float* Qg = (const float*)d_in[0];
  const float* Kg = (const float*)d_in[1];
  const float* Vg = (const float*)d_in[2];
  const float* Bg = (const float*)d_in[3];
  const float* Wg = (const float*)d_in[4];
  float* out = (float*)d_out;

  short* comb = (short*)d_ws;                          //  8 MB bf16 [4096][1024]
  short* Wt   = comb + (size_t)(2 * S) * D;            //  2 MB bf16 [1024][1024]
  short* KVb  = Wt   + (size_t)D * D;                  // 16 MB interleaved K/V frags

  kv_prep<<<dim3(NT, H, 2), 256, 0, stream>>>(Kg, Vg, KVb);
  wt_kernel<<<dim3(D / 64, D / 64), 256, 0, stream>>>(Wg, Wt);
  attn_fused<<<dim3(1024), 256, 0, stream>>>(Qg, Bg, KVb, comb);
  proj_gemm<<<dim3(32, 16), 256, 0, stream>>>(comb, Wt, out);
}